// Round 10
// baseline (1158.532 us; speedup 1.0000x reference)
//
#include <hip/hip_runtime.h>
#include <math.h>

#define NN 20000
#define FF 32
#define TT 12
#define HH 64
#define EE 320000
#define OUTD 12
#define CB 313   // ceil(NN/64)

typedef __attribute__((ext_vector_type(8))) short short8;
typedef __attribute__((ext_vector_type(4))) float floatx4;

__device__ __forceinline__ float sigmoidf_(float x) { return 1.f / (1.f + expf(-x)); }

__device__ __forceinline__ unsigned short bf16rne(float f) {
    union { float f; unsigned u; } v; v.f = f;
    unsigned u = v.u;
    u += 0x7fffu + ((u >> 16) & 1u);
    return (unsigned short)(u >> 16);
}
__device__ __forceinline__ float lof(unsigned v) {
    union { unsigned u; float f; } x; x.u = v << 16; return x.f;
}
__device__ __forceinline__ float hif(unsigned v) {
    union { unsigned u; float f; } x; x.u = v & 0xffff0000u; return x.f;
}
__device__ __forceinline__ unsigned packbf(float a, float b) {
    return (unsigned)bf16rne(a) | ((unsigned)bf16rne(b) << 16);
}

#define MFMA(a, b, c) __builtin_amdgcn_mfma_f32_16x16x32_bf16((a), (b), (c), 0, 0, 0)

// ---------------- preprocessing ----------------

__global__ void deg_init_kernel(float* deg) {
    int i = blockIdx.x * 256 + threadIdx.x;
    if (i < NN) deg[i] = 1.0f;
}

__global__ void edge_accum_kernel(const int* ei, const float* ea, float* deg, int* cnt) {
    int e = blockIdx.x * 256 + threadIdx.x;
    if (e >= EE) return;
    int d = ei[EE + e];
    float w = ea[e * 2 + 1];
    atomicAdd(&deg[d], w);
    atomicAdd(&cnt[d], 1);
}

__global__ void dinv_kernel(const float* deg, float* dinv) {
    int i = blockIdx.x * 256 + threadIdx.x;
    if (i < NN) dinv[i] = rsqrtf(deg[i]);
}

__global__ void scan_kernel(const int* cnt, int* rowptr, int* cursor) {
    __shared__ int wsum[16];
    int tid = threadIdx.x;
    int lane = tid & 63, w = tid >> 6;
    int run = 0;
    for (int base = 0; base < NN; base += 1024) {
        int idx = base + tid;
        int c = (idx < NN) ? cnt[idx] : 0;
        int v = c;
        #pragma unroll
        for (int off = 1; off < 64; off <<= 1) {
            int t = __shfl_up(v, off, 64);
            if (lane >= off) v += t;
        }
        if (lane == 63) wsum[w] = v;
        __syncthreads();
        if (tid < 16) {
            int x = wsum[tid];
            #pragma unroll
            for (int off = 1; off < 16; off <<= 1) {
                int t = __shfl_up(x, off, 64);
                if (tid >= off) x += t;
            }
            wsum[tid] = x;
        }
        __syncthreads();
        int waveoff = (w > 0) ? wsum[w - 1] : 0;
        int excl = run + waveoff + (v - c);
        if (idx < NN) { rowptr[idx] = excl; cursor[idx] = excl; }
        run += wsum[15];
        __syncthreads();
    }
    if (tid == 0) rowptr[NN] = run;
}

__global__ void fill_kernel(const int* ei, const float* ea, const float* dinv,
                            int* cursor, int* colIdx, float* valArr) {
    int e = blockIdx.x * 256 + threadIdx.x;
    if (e >= EE) return;
    int s = ei[e], d = ei[EE + e];
    float w = ea[e * 2 + 1];
    int pos = atomicAdd(&cursor[d], 1);
    colIdx[pos] = s;
    valArr[pos] = dinv[s] * w * dinv[d];
}

// x (N,F,T) fp32 -> xTs (T,N,F) bf16
__global__ void transpose_kernel(const float* x, unsigned short* xTs) {
    int i = blockIdx.x * 256 + threadIdx.x;
    if (i >= TT * NN * FF) return;
    int f = i & 31;
    int rest = i >> 5;
    int n = rest % NN;
    int t = rest / NN;
    xTs[i] = bf16rne(x[n * (FF * TT) + f * TT + t]);
}

// all 9 weight conversions in one launch; *T variants transpose (K,64)->[64][K]
__global__ void wconv_all(const float* Wg0, const float* Wu0, const float* Wr0, const float* Wc0,
                          const float* Wg1, const float* Wu1, const float* Wr1, const float* Wc1,
                          const float* ipw,
                          short* Wg0T, short* Wu0T, short* Wr0T, short* Wc0T,
                          short* Wg1T, short* Wu1T, short* Wr1T, short* Wc1T, short* ipwB) {
    int i = blockIdx.x * 256 + threadIdx.x;
    if (i < 2048) { int n = i / 32, k = i % 32; Wg0T[i] = (short)bf16rne(Wg0[k * 64 + n]); return; }
    i -= 2048;
    if (i < 10240) { int n = i / 160, k = i % 160; Wu0T[i] = (short)bf16rne(Wu0[k * 64 + n]); return; }
    i -= 10240;
    if (i < 10240) { int n = i / 160, k = i % 160; Wr0T[i] = (short)bf16rne(Wr0[k * 64 + n]); return; }
    i -= 10240;
    if (i < 10240) { int n = i / 160, k = i % 160; Wc0T[i] = (short)bf16rne(Wc0[k * 64 + n]); return; }
    i -= 10240;
    if (i < 4096) { int n = i / 64, k = i % 64; Wg1T[i] = (short)bf16rne(Wg1[k * 64 + n]); return; }
    i -= 4096;
    if (i < 12288) { int n = i / 192, k = i % 192; Wu1T[i] = (short)bf16rne(Wu1[k * 64 + n]); return; }
    i -= 12288;
    if (i < 12288) { int n = i / 192, k = i % 192; Wr1T[i] = (short)bf16rne(Wr1[k * 64 + n]); return; }
    i -= 12288;
    if (i < 12288) { int n = i / 192, k = i % 192; Wc1T[i] = (short)bf16rne(Wc1[k * 64 + n]); return; }
    i -= 12288;
    if (i < 12288) { ipwB[i] = (short)bf16rne(ipw[i]); }
}

// fold output projections: OW2[k][d] = sum_j opw[j][k]*ow[j][d]; ob2[d] = sum_j opb[j]*ow[j][d] + ob[d]
__global__ void fold_out(const float* opw, const float* opb, const float* ow, const float* ob,
                         float* OW2, float* ob2) {
    int i = blockIdx.x * 256 + threadIdx.x;
    if (i < 64 * OUTD) {
        int k = i / OUTD, d = i - k * OUTD;
        float acc = 0.f;
        for (int j = 0; j < 64; ++j) acc += opw[j * 64 + k] * ow[j * OUTD + d];
        OW2[i] = acc;
    } else if (i < 64 * OUTD + OUTD) {
        int d = i - 64 * OUTD;
        float acc = ob[d];
        for (int j = 0; j < 64; ++j) acc += opb[j] * ow[j * OUTD + d];
        ob2[d] = acc;
    }
}

// bf16 aggregation over x planes: 16 lanes/node, 2 features per lane
__global__ void gather_raw32(const unsigned short* __restrict__ xTs, const float* __restrict__ dinv,
                             const int* __restrict__ rowptr, const int* __restrict__ colIdx,
                             const float* __restrict__ valArr, unsigned short* __restrict__ aggxs) {
    const unsigned* src = (const unsigned*)(xTs + (size_t)blockIdx.y * NN * 32);
    unsigned* dst = (unsigned*)(aggxs + (size_t)blockIdx.y * NN * 32);
    int node = blockIdx.x * 16 + (threadIdx.x >> 4);
    int l2 = threadIdx.x & 15;
    float di = dinv[node];
    float dd = di * di;
    unsigned v = src[node * 16 + l2];
    float a0 = dd * lof(v), a1 = dd * hif(v);
    int s = rowptr[node], e = rowptr[node + 1];
    int j = s;
    for (; j + 3 < e; j += 4) {
        int c0 = colIdx[j], c1 = colIdx[j + 1], c2 = colIdx[j + 2], c3 = colIdx[j + 3];
        float w0 = valArr[j], w1 = valArr[j + 1], w2 = valArr[j + 2], w3 = valArr[j + 3];
        unsigned v0 = src[c0 * 16 + l2], v1 = src[c1 * 16 + l2];
        unsigned v2 = src[c2 * 16 + l2], v3 = src[c3 * 16 + l2];
        a0 += w0 * lof(v0) + w1 * lof(v1) + w2 * lof(v2) + w3 * lof(v3);
        a1 += w0 * hif(v0) + w1 * hif(v1) + w2 * hif(v2) + w3 * hif(v3);
    }
    for (; j < e; ++j) {
        unsigned vv = src[colIdx[j] * 16 + l2];
        float w = valArr[j];
        a0 += w * lof(vv); a1 += w * hif(vv);
    }
    dst[node * 16 + l2] = packbf(a0, a1);
}

// ---------------- MFMA kernels ----------------
// A[m=lane&15][k=quad*8+j]; B^T[n=lane&15][k=quad*8+j]; C/D: col=lane&15, row=quad*4+reg.

// g0all = sigmoid(aggx @ Wg0 + bg0) -> bf16, rows = T*N, K=32
__launch_bounds__(256, 4)
__global__ void mfma_g0(const unsigned short* __restrict__ aggxs, const short* __restrict__ Wg0T,
                        const float* __restrict__ bg0, unsigned short* __restrict__ g0s) {
    int tid = threadIdx.x;
    int wv = tid >> 6, lane = tid & 63;
    int quad = lane >> 4, ln = lane & 15;
    int m0 = blockIdx.x * 64 + wv * 16;
    short8 af = *reinterpret_cast<const short8*>(aggxs + (size_t)(m0 + ln) * 32 + quad * 8);
    floatx4 z = {0.f, 0.f, 0.f, 0.f};
    floatx4 acc[4] = {z, z, z, z};
    #pragma unroll
    for (int ct = 0; ct < 4; ++ct) {
        short8 bf = *reinterpret_cast<const short8*>(Wg0T + (size_t)(ct * 16 + ln) * 32 + quad * 8);
        acc[ct] = MFMA(af, bf, acc[ct]);
    }
    #pragma unroll
    for (int ct = 0; ct < 4; ++ct) {
        int col = ct * 16 + ln;
        float bb = bg0[col];
        #pragma unroll
        for (int r = 0; r < 4; ++r) {
            int row = m0 + quad * 4 + r;
            g0s[(size_t)row * 64 + col] = bf16rne(sigmoidf_(acc[ct][r] + bb));
        }
    }
}

// ---- cell bodies (per-wave 16-row tile, wave-private LDS slice T) ----

__device__ __forceinline__ void cell0_body(
    int m0, short* T,
    const unsigned short* __restrict__ xt, const unsigned short* __restrict__ g0,
    const float* __restrict__ h0f, const unsigned short* __restrict__ h0s,
    const short* __restrict__ Wu0T, const short* __restrict__ Wr0T,
    const short* __restrict__ Wc0T, const short* __restrict__ Wg1T,
    const float* __restrict__ bu0, const float* __restrict__ br0,
    const float* __restrict__ bc0,
    float* __restrict__ h0nf, unsigned short* __restrict__ h0ns,
    unsigned short* __restrict__ y0s) {
    int lane = threadIdx.x & 63;
    int quad = lane >> 4, ln = lane & 15;
    int arow = m0 + ln; if (arow > NN - 1) arow = NN - 1;

    short8 af[5];
    af[0] = *reinterpret_cast<const short8*>(xt + (size_t)arow * 32 + quad * 8);
    af[1] = *reinterpret_cast<const short8*>(g0 + (size_t)arow * 64 + quad * 8);
    af[2] = *reinterpret_cast<const short8*>(g0 + (size_t)arow * 64 + 32 + quad * 8);
    af[3] = *reinterpret_cast<const short8*>(h0s + (size_t)arow * 64 + quad * 8);
    af[4] = *reinterpret_cast<const short8*>(h0s + (size_t)arow * 64 + 32 + quad * 8);

    floatx4 z = {0.f, 0.f, 0.f, 0.f};
    floatx4 aU[4] = {z, z, z, z};
    floatx4 aR[4] = {z, z, z, z};
    #pragma unroll
    for (int ct = 0; ct < 4; ++ct) {
        const short* bu = Wu0T + (size_t)(ct * 16 + ln) * 160;
        const short* br = Wr0T + (size_t)(ct * 16 + ln) * 160;
        #pragma unroll
        for (int kc = 0; kc < 5; ++kc) {
            int ko = kc * 32 + quad * 8;
            aU[ct] = MFMA(af[kc], *reinterpret_cast<const short8*>(bu + ko), aU[ct]);
            aR[ct] = MFMA(af[kc], *reinterpret_cast<const short8*>(br + ko), aR[ct]);
        }
    }
    float uu[4][4];
    #pragma unroll
    for (int ct = 0; ct < 4; ++ct) {
        int col = ct * 16 + ln;
        float bU = bu0[col], bR = br0[col];
        #pragma unroll
        for (int r = 0; r < 4; ++r) {
            int grow = m0 + quad * 4 + r;
            bool ok = grow < NN;
            uu[ct][r] = sigmoidf_(aU[ct][r] + bU);
            float hv = ok ? h0f[(size_t)grow * 64 + col] : 0.f;
            float rh = sigmoidf_(aR[ct][r] + bR) * hv;
            T[(quad * 4 + r) * 72 + col] = (short)bf16rne(rh);
        }
    }
    __threadfence_block();

    short8 ar0 = *reinterpret_cast<const short8*>(T + ln * 72 + quad * 8);
    short8 ar1 = *reinterpret_cast<const short8*>(T + ln * 72 + 32 + quad * 8);
    floatx4 aC[4] = {z, z, z, z};
    #pragma unroll
    for (int ct = 0; ct < 4; ++ct) {
        const short* bc = Wc0T + (size_t)(ct * 16 + ln) * 160;
        #pragma unroll
        for (int kc = 0; kc < 3; ++kc)
            aC[ct] = MFMA(af[kc], *reinterpret_cast<const short8*>(bc + kc * 32 + quad * 8), aC[ct]);
        aC[ct] = MFMA(ar0, *reinterpret_cast<const short8*>(bc + 96 + quad * 8), aC[ct]);
        aC[ct] = MFMA(ar1, *reinterpret_cast<const short8*>(bc + 128 + quad * 8), aC[ct]);
    }
    __threadfence_block();
    #pragma unroll
    for (int ct = 0; ct < 4; ++ct) {
        int col = ct * 16 + ln;
        float bC = bc0[col];
        #pragma unroll
        for (int r = 0; r < 4; ++r) {
            int grow = m0 + quad * 4 + r;
            bool ok = grow < NN;
            float hv = ok ? h0f[(size_t)grow * 64 + col] : 0.f;
            float cv = tanhf(aC[ct][r] + bC);
            float hn = uu[ct][r] * hv + (1.f - uu[ct][r]) * cv;
            unsigned short hb = bf16rne(hn);
            if (ok) {
                h0nf[(size_t)grow * 64 + col] = hn;
                h0ns[(size_t)grow * 64 + col] = hb;
            }
            T[(quad * 4 + r) * 72 + col] = (short)hb;
        }
    }
    __threadfence_block();

    short8 ah0 = *reinterpret_cast<const short8*>(T + ln * 72 + quad * 8);
    short8 ah1 = *reinterpret_cast<const short8*>(T + ln * 72 + 32 + quad * 8);
    floatx4 aY[4] = {z, z, z, z};
    #pragma unroll
    for (int ct = 0; ct < 4; ++ct) {
        const short* bg = Wg1T + (size_t)(ct * 16 + ln) * 64;
        aY[ct] = MFMA(ah0, *reinterpret_cast<const short8*>(bg + quad * 8), aY[ct]);
        aY[ct] = MFMA(ah1, *reinterpret_cast<const short8*>(bg + 32 + quad * 8), aY[ct]);
    }
    #pragma unroll
    for (int ct = 0; ct < 4; ++ct) {
        int col = ct * 16 + ln;
        #pragma unroll
        for (int r = 0; r < 4; ++r) {
            int grow = m0 + quad * 4 + r;
            if (grow < NN) y0s[(size_t)grow * 64 + col] = bf16rne(aY[ct][r]);
        }
    }
}

// cell1 with g1 read from LDS tile G1 (stride 72 shorts, rows = block-local nodes)
__device__ __forceinline__ void cell1_body(
    int m0, short* T, const short* G1,
    const unsigned short* __restrict__ h0s,
    const float* __restrict__ h1f, const unsigned short* __restrict__ h1s,
    const short* __restrict__ Wu1T, const short* __restrict__ Wr1T,
    const short* __restrict__ Wc1T,
    const float* __restrict__ bu1, const float* __restrict__ br1,
    const float* __restrict__ bc1,
    float* __restrict__ h1nf, unsigned short* __restrict__ h1ns) {
    int lane = threadIdx.x & 63;
    int wv = threadIdx.x >> 6;
    int quad = lane >> 4, ln = lane & 15;
    int arow = m0 + ln; if (arow > NN - 1) arow = NN - 1;
    int lrow = wv * 16 + ln;   // block-local node for G1

    short8 af[6];
    af[0] = *reinterpret_cast<const short8*>(h0s + (size_t)arow * 64 + quad * 8);
    af[1] = *reinterpret_cast<const short8*>(h0s + (size_t)arow * 64 + 32 + quad * 8);
    af[2] = *reinterpret_cast<const short8*>(G1 + lrow * 72 + quad * 8);
    af[3] = *reinterpret_cast<const short8*>(G1 + lrow * 72 + 32 + quad * 8);
    af[4] = *reinterpret_cast<const short8*>(h1s + (size_t)arow * 64 + quad * 8);
    af[5] = *reinterpret_cast<const short8*>(h1s + (size_t)arow * 64 + 32 + quad * 8);

    floatx4 z = {0.f, 0.f, 0.f, 0.f};
    floatx4 aU[4] = {z, z, z, z};
    floatx4 aR[4] = {z, z, z, z};
    #pragma unroll
    for (int ct = 0; ct < 4; ++ct) {
        const short* bu = Wu1T + (size_t)(ct * 16 + ln) * 192;
        const short* br = Wr1T + (size_t)(ct * 16 + ln) * 192;
        #pragma unroll
        for (int kc = 0; kc < 6; ++kc) {
            int ko = kc * 32 + quad * 8;
            aU[ct] = MFMA(af[kc], *reinterpret_cast<const short8*>(bu + ko), aU[ct]);
            aR[ct] = MFMA(af[kc], *reinterpret_cast<const short8*>(br + ko), aR[ct]);
        }
    }
    float uu[4][4];
    #pragma unroll
    for (int ct = 0; ct < 4; ++ct) {
        int col = ct * 16 + ln;
        float bU = bu1[col], bR = br1[col];
        #pragma unroll
        for (int r = 0; r < 4; ++r) {
            int grow = m0 + quad * 4 + r;
            bool ok = grow < NN;
            uu[ct][r] = sigmoidf_(aU[ct][r] + bU);
            float hv = ok ? h1f[(size_t)grow * 64 + col] : 0.f;
            float rh = sigmoidf_(aR[ct][r] + bR) * hv;
            T[(quad * 4 + r) * 72 + col] = (short)bf16rne(rh);
        }
    }
    __threadfence_block();

    short8 ar0 = *reinterpret_cast<const short8*>(T + ln * 72 + quad * 8);
    short8 ar1 = *reinterpret_cast<const short8*>(T + ln * 72 + 32 + quad * 8);
    floatx4 aC[4] = {z, z, z, z};
    #pragma unroll
    for (int ct = 0; ct < 4; ++ct) {
        const short* bc = Wc1T + (size_t)(ct * 16 + ln) * 192;
        #pragma unroll
        for (int kc = 0; kc < 4; ++kc)
            aC[ct] = MFMA(af[kc], *reinterpret_cast<const short8*>(bc + kc * 32 + quad * 8), aC[ct]);
        aC[ct] = MFMA(ar0, *reinterpret_cast<const short8*>(bc + 128 + quad * 8), aC[ct]);
        aC[ct] = MFMA(ar1, *reinterpret_cast<const short8*>(bc + 160 + quad * 8), aC[ct]);
    }
    #pragma unroll
    for (int ct = 0; ct < 4; ++ct) {
        int col = ct * 16 + ln;
        float bC = bc1[col];
        #pragma unroll
        for (int r = 0; r < 4; ++r) {
            int grow = m0 + quad * 4 + r;
            if (grow >= NN) continue;
            float hv = h1f[(size_t)grow * 64 + col];
            float cv = tanhf(aC[ct][r] + bC);
            float hn = uu[ct][r] * hv + (1.f - uu[ct][r]) * cv;
            h1nf[(size_t)grow * 64 + col] = hn;
            h1ns[(size_t)grow * 64 + col] = bf16rne(hn);
        }
    }
}

// standalone cell0 (t=0 bootstrap)
__launch_bounds__(256, 6)
__global__ void mfma_cell0(const unsigned short* xt, const unsigned short* g0,
                           const float* h0f, const unsigned short* h0s,
                           const short* Wu0T, const short* Wr0T, const short* Wc0T, const short* Wg1T,
                           const float* bu0, const float* br0, const float* bc0,
                           float* h0nf, unsigned short* h0ns, unsigned short* y0s) {
    __shared__ short lds[4 * 16 * 72];
    int wv = threadIdx.x >> 6;
    cell0_body(blockIdx.x * 64 + wv * 16, lds + wv * (16 * 72),
               xt, g0, h0f, h0s, Wu0T, Wr0T, Wc0T, Wg1T, bu0, br0, bc0, h0nf, h0ns, y0s);
}

// merged step: blocks [0,CB) = {gather g1 -> LDS, then cell1 for t}; blocks [CB,2CB) = cell0 for t+1
__launch_bounds__(256, 6)
__global__ void mfma_step(
    const unsigned short* y0s, const float* dinv, const int* rowptr,
    const int* colIdx, const float* valArr, const float* bg1,
    const unsigned short* h0s_cur,
    const float* h1f_in, const unsigned short* h1s_in,
    const short* Wu1T, const short* Wr1T, const short* Wc1T,
    const float* bu1, const float* br1, const float* bc1,
    float* h1f_out, unsigned short* h1s_out,
    const unsigned short* xt_next, const unsigned short* g0_next, const float* h0f_cur,
    const short* Wu0T, const short* Wr0T, const short* Wc0T, const short* Wg1T,
    const float* bu0, const float* br0, const float* bc0,
    float* h0f_next, unsigned short* h0s_next, unsigned short* y0s_next) {
    __shared__ short lds[4 * 16 * 72];
    __shared__ short G1t[64 * 72];
    int tid = threadIdx.x;
    int wv = tid >> 6;
    short* T = lds + wv * (16 * 72);
    if (blockIdx.x < CB) {
        int row0 = blockIdx.x * 64;
        // ---- cooperative gather: 8 nodes per 256-thread round, 32 lanes/node ----
        const unsigned* yp = (const unsigned*)y0s;
        int sub = tid >> 5;        // 0..7
        int l2 = tid & 31;         // 2 features per lane
        #pragma unroll
        for (int rnd = 0; rnd < 8; ++rnd) {
            int nl = rnd * 8 + sub;
            int node = row0 + nl;
            int nc = (node < NN) ? node : (NN - 1);
            float di = dinv[nc];
            float dd = di * di;
            unsigned v = yp[nc * 32 + l2];
            float a0 = dd * lof(v), a1 = dd * hif(v);
            int s = rowptr[nc], e = rowptr[nc + 1];
            int j = s;
            for (; j + 3 < e; j += 4) {
                int c0 = colIdx[j], c1 = colIdx[j + 1], c2 = colIdx[j + 2], c3 = colIdx[j + 3];
                float w0 = valArr[j], w1 = valArr[j + 1], w2 = valArr[j + 2], w3 = valArr[j + 3];
                unsigned v0 = yp[c0 * 32 + l2], v1 = yp[c1 * 32 + l2];
                unsigned v2 = yp[c2 * 32 + l2], v3 = yp[c3 * 32 + l2];
                a0 += w0 * lof(v0) + w1 * lof(v1) + w2 * lof(v2) + w3 * lof(v3);
                a1 += w0 * hif(v0) + w1 * hif(v1) + w2 * hif(v2) + w3 * hif(v3);
            }
            for (; j < e; ++j) {
                unsigned vv = yp[colIdx[j] * 32 + l2];
                float w = valArr[j];
                a0 += w * lof(vv); a1 += w * hif(vv);
            }
            float gl = sigmoidf_(a0 + bg1[2 * l2]);
            float gh = sigmoidf_(a1 + bg1[2 * l2 + 1]);
            ((unsigned*)G1t)[nl * 36 + l2] = packbf(gl, gh);
        }
        __syncthreads();
        cell1_body(row0 + wv * 16, T, G1t, h0s_cur, h1f_in, h1s_in,
                   Wu1T, Wr1T, Wc1T, bu1, br1, bc1, h1f_out, h1s_out);
    } else {
        cell0_body((blockIdx.x - CB) * 64 + wv * 16, T, xt_next, g0_next, h0f_cur, h0s_cur,
                   Wu0T, Wr0T, Wc0T, Wg1T, bu0, br0, bc0, h0f_next, h0s_next, y0s_next);
    }
}

// ---------------- fused qkv + attention: one wave per node ----------------
__launch_bounds__(256, 5)
__global__ void attn_fused(const unsigned short* __restrict__ hseqs,
                           const short* __restrict__ ipwB, const float* __restrict__ ipb,
                           const float* __restrict__ OW2, const float* __restrict__ ob2,
                           float* __restrict__ out) {
    __shared__ unsigned short qtile[4][16 * 200];
    __shared__ float fbuf[4][64];
    int wv = threadIdx.x >> 6, lane = threadIdx.x & 63;
    int node = blockIdx.x * 4 + wv;
    int quad = lane >> 4, ln = lane & 15;
    unsigned short* q = qtile[wv];
    float* sob = fbuf[wv];       // obar[64]
    __shared__ float wbuf[4][32];
    float* W = wbuf[wv];         // [2][16] head-major mean-prob weights

    // ---- qkv tile via MFMA from hseqs ----
    short8 zero8 = {0, 0, 0, 0, 0, 0, 0, 0};
    short8 af0 = zero8, af1 = zero8;
    if (ln < TT) {
        const unsigned short* hp = hseqs + ((size_t)ln * NN + node) * 64;
        af0 = *reinterpret_cast<const short8*>(hp + quad * 8);
        af1 = *reinterpret_cast<const short8*>(hp + 32 + quad * 8);
    }
    floatx4 z = {0.f, 0.f, 0.f, 0.f};
    #pragma unroll
    for (int ct = 0; ct < 12; ++ct) {
        const short* br = ipwB + (size_t)(ct * 16 + ln) * 64;
        floatx4 acc = MFMA(af0, *reinterpret_cast<const short8*>(br + quad * 8), z);
        acc = MFMA(af1, *reinterpret_cast<const short8*>(br + 32 + quad * 8), acc);
        int col = ct * 16 + ln;
        float bb = ipb[col];
        #pragma unroll
        for (int r = 0; r < 4; ++r)
            q[(quad * 4 + r) * 200 + col] = bf16rne(acc[r] + bb);
    }
    __threadfence_block();

    // ---- scores per head via one MFMA ----
    floatx4 sc[2];
    #pragma unroll
    for (int h = 0; h < 2; ++h) {
        short8 aQ = *reinterpret_cast<const short8*>(q + ln * 200 + h * 32 + quad * 8);
        short8 bK = *reinterpret_cast<const short8*>(q + ln * 200 + 64 + h * 32 + quad * 8);
        sc[h] = MFMA(aQ, bK, z);   // rows=tq(quad*4+r), cols=ts(ln)
    }
    const float scl = 0.17677669529663687f;
    bool colok = ln < 12;
    #pragma unroll
    for (int h = 0; h < 2; ++h) {
        float p[4];
        #pragma unroll
        for (int r = 0; r < 4; ++r) {
            float v = colok ? sc[h][r] * scl : -1e30f;
            float m = v;
            m = fmaxf(m, __shfl_xor(m, 1, 64));
            m = fmaxf(m, __shfl_xor(m, 2, 64));
            m = fmaxf(m, __shfl_xor(m, 4, 64));
            m = fmaxf(m, __shfl_xor(m, 8, 64));
            float e = colok ? expf(v - m) : 0.f;
            float s = e;
            s += __shfl_xor(s, 1, 64);
            s += __shfl_xor(s, 2, 64);
            s += __shfl_xor(s, 4, 64);
            s += __shfl_xor(s, 8, 64);
            p[r] = e / s;
        }
        float ts = (quad < 3) ? (p[0] + p[1] + p[2] + p[3]) : 0.f;
        ts += __shfl_xor(ts, 16, 64);
        ts += __shfl_xor(ts, 32, 64);
        if (quad == 0) W[h * 16 + ln] = ts * (1.f / 12.f);
    }
    __threadfence_block();

    // ---- obar[d] = sum_ts w[hd][ts] * V[ts][d] ----
    {
        int d = lane, hd = d >> 5, dd = d & 31;
        float acc = 0.f;
        #pragma unroll
        for (int ts = 0; ts < 12; ++ts)
            acc += W[hd * 16 + ts] * lof((unsigned)q[ts * 200 + 128 + hd * 32 + dd]);
        sob[d] = acc;
    }
    __threadfence_block();

    // ---- out = obar @ OW2 + ob2 (folded projections) ----
    if (lane < OUTD) {
        float acc = ob2[lane];
        #pragma unroll
        for (int k = 0; k < 64; ++k) acc += sob[k] * OW2[k * OUTD + lane];
        out[(size_t)node * OUTD + lane] = acc;
    }
}

// ---------------- launcher ----------------

extern "C" void kernel_launch(void* const* d_in, const int* in_sizes, int n_in,
                              void* d_out, int out_size, void* d_ws, size_t ws_size,
                              hipStream_t stream) {
    const float* x   = (const float*)d_in[0];
    const int*   ei  = (const int*)d_in[1];
    const float* ea  = (const float*)d_in[2];
    const float* Wg0 = (const float*)d_in[3];
    const float* bg0 = (const float*)d_in[4];
    const float* Wu0 = (const float*)d_in[5];
    const float* bu0 = (const float*)d_in[6];
    const float* Wr0 = (const float*)d_in[7];
    const float* br0 = (const float*)d_in[8];
    const float* Wc0 = (const float*)d_in[9];
    const float* bc0 = (const float*)d_in[10];
    const float* Wg1 = (const float*)d_in[11];
    const float* bg1 = (const float*)d_in[12];
    const float* Wu1 = (const float*)d_in[13];
    const float* bu1 = (const float*)d_in[14];
    const float* Wr1 = (const float*)d_in[15];
    const float* br1 = (const float*)d_in[16];
    const float* Wc1 = (const float*)d_in[17];
    const float* bc1 = (const float*)d_in[18];
    const float* ipw = (const float*)d_in[19];
    const float* ipb = (const float*)d_in[20];
    const float* opw = (const float*)d_in[21];
    const float* opb = (const float*)d_in[22];
    const float* ow  = (const float*)d_in[23];
    const float* ob  = (const float*)d_in[24];
    float* out = (float*)d_out;

    char* p = (char*)d_ws;
    auto alloc = [&](size_t bytes) { char* r = p; p += (bytes + 255) & ~(size_t)255; return (void*)r; };
    unsigned short* hseqs = (unsigned short*)alloc((size_t)TT * NN * HH * 2);
    unsigned short* h1s0  = (unsigned short*)alloc((size_t)NN * HH * 2);
    short* Wg0T = (short*)alloc((size_t)64 * 32 * 2);
    short* Wu0T = (short*)alloc((size_t)64 * 160 * 2);
    short* Wr0T = (short*)alloc((size_t)64 * 160 * 2);
    short* Wc0T = (short*)alloc((size_t)64 * 160 * 2);
    short* Wg1T = (short*)alloc((size_t)64 * 64 * 2);
    short* Wu1T = (short*)alloc((size_t)64 * 192 * 2);
    short* Wr1T = (short*)alloc((size_t)64 * 192 * 2);
    short* Wc1T = (short*)alloc((size_t)64 * 192 * 2);
    short* ipwB = (short*)alloc((size_t)192 * 64 * 2);
    float* OW2  = (float*)alloc((size_t)64 * OUTD * 4);
    float* ob2  = (float*)alloc((size_t)OUTD * 4);
    float* dinv   = (float*)alloc((size_t)NN * 4);
    int*   rowptr = (int*)  alloc((size_t)(NN + 1) * 4);
    int*   colIdx = (int*)  alloc((size_t)EE * 4);
    float* valArr = (float*)alloc((size_t)EE * 4);
    unsigned short* xTs   = (unsigned short*)alloc((size_t)TT * NN * FF * 2);
    unsigned short* aggxs = (unsigned short*)alloc((size_t)TT * NN * FF * 2);
    unsigned short* g0s   = (unsigned short*)alloc((size_t)TT * NN * HH * 2);
    float* deg    = (float*)alloc((size_t)NN * 4);
    int*   cnt    = (int*)  alloc((size_t)NN * 4);
    int*   cursor = (int*)  alloc((size_t)NN * 4);
    unsigned short* y0s = (unsigned short*)alloc((size_t)NN * HH * 2);
    float* h0f0 = (float*)alloc((size_t)NN * HH * 4);
    float* h0f1 = (float*)alloc((size_t)NN * HH * 4);
    float* h1f0 = (float*)alloc((size_t)NN * HH * 4);
    float* h1f1 = (float*)alloc((size_t)NN * HH * 4);
    unsigned short* h0s0 = (unsigned short*)alloc((size_t)NN * HH * 2);
    unsigned short* h0s1 = (unsigned short*)alloc((size_t)NN * HH * 2);
    (void)ws_size;

    hipMemsetAsync(cnt, 0, (size_t)NN * 4, stream);
    hipMemsetAsync(h0f1, 0, (size_t)NN * HH * 4, stream);
    hipMemsetAsync(h1f1, 0, (size_t)NN * HH * 4, stream);
    hipMemsetAsync(h0s1, 0, (size_t)NN * HH * 2, stream);
    hipMemsetAsync(h1s0, 0, (size_t)NN * HH * 2, stream);
    deg_init_kernel<<<(NN + 255) / 256, 256, 0, stream>>>(deg);
    edge_accum_kernel<<<(EE + 255) / 256, 256, 0, stream>>>(ei, ea, deg, cnt);
    dinv_kernel<<<(NN + 255) / 256, 256, 0, stream>>>(deg, dinv);
    scan_kernel<<<1, 1024, 0, stream>>>(cnt, rowptr, cursor);
    fill_kernel<<<(EE + 255) / 256, 256, 0, stream>>>(ei, ea, dinv, cursor, colIdx, valArr);
    transpose_kernel<<<(TT * NN * FF + 255) / 256, 256, 0, stream>>>(x, xTs);
    wconv_all<<<(86016 + 255) / 256, 256, 0, stream>>>(
        Wg0, Wu0, Wr0, Wc0, Wg1, Wu1, Wr1, Wc1, ipw,
        Wg0T, Wu0T, Wr0T, Wc0T, Wg1T, Wu1T, Wr1T, Wc1T, ipwB);
    fold_out<<<4, 256, 0, stream>>>(opw, opb, ow, ob, OW2, ob2);

    gather_raw32<<<dim3(NN / 16, TT), 256, 0, stream>>>(xTs, dinv, rowptr, colIdx, valArr, aggxs);
    mfma_g0<<<(TT * NN) / 64, 256, 0, stream>>>(aggxs, Wg0T, bg0, g0s);

    float* h0f[2] = {h0f0, h0f1};
    unsigned short* h0s[2] = {h0s0, h0s1};
    float* h1f[2] = {h1f0, h1f1};

    // C0[0]: reads zeroed buf[1], writes buf[0]
    mfma_cell0<<<CB, 256, 0, stream>>>(
        xTs, g0s, h0f[1], h0s[1], Wu0T, Wr0T, Wc0T, Wg1T, bu0, br0, bc0,
        h0f[0], h0s[0], y0s);

    for (int t = 0; t < TT; ++t) {
        int tn = (t < TT - 1) ? (t + 1) : t;
        int grid = (t < TT - 1) ? 2 * CB : CB;
        mfma_step<<<grid, 256, 0, stream>>>(
            y0s, dinv, rowptr, colIdx, valArr, bg1,
            h0s[t & 1], h1f[(t + 1) & 1],
            (t == 0) ? h1s0 : (hseqs + (size_t)(t - 1) * NN * HH),
            Wu1T, Wr1T, Wc1T, bu1, br1, bc1,
            h1f[t & 1], hseqs + (size_t)t * NN * HH,
            xTs + (size_t)tn * NN * FF, g0s + (size_t)tn * NN * HH, h0f[t & 1],
            Wu0T, Wr0T, Wc0T, Wg1T, bu0, br0, bc0,
            h0f[(t + 1) & 1], h0s[(t + 1) & 1], y0s);
    }

    attn_fused<<<NN / 4, 256, 0, stream>>>(hseqs, ipwB, ipb, OW2, ob2, out);
}

// Round 11
// 968.878 us; speedup vs baseline: 1.1957x; 1.1957x over previous
//
#include <hip/hip_runtime.h>
#include <math.h>

#define NN 20000
#define FF 32
#define TT 12
#define HH 64
#define EE 320000
#define OUTD 12
#define CB 313   // ceil(NN/64)

typedef __attribute__((ext_vector_type(8))) short short8;
typedef __attribute__((ext_vector_type(4))) float floatx4;

__device__ __forceinline__ float sigmoidf_(float x) { return 1.f / (1.f + expf(-x)); }

__device__ __forceinline__ unsigned short bf16rne(float f) {
    union { float f; unsigned u; } v; v.f = f;
    unsigned u = v.u;
    u += 0x7fffu + ((u >> 16) & 1u);
    return (unsigned short)(u >> 16);
}
__device__ __forceinline__ float lof(unsigned v) {
    union { unsigned u; float f; } x; x.u = v << 16; return x.f;
}
__device__ __forceinline__ float hif(unsigned v) {
    union { unsigned u; float f; } x; x.u = v & 0xffff0000u; return x.f;
}
__device__ __forceinline__ unsigned packbf(float a, float b) {
    return (unsigned)bf16rne(a) | ((unsigned)bf16rne(b) << 16);
}

#define MFMA(a, b, c) __builtin_amdgcn_mfma_f32_16x16x32_bf16((a), (b), (c), 0, 0, 0)

// ---------------- preprocessing ----------------

__global__ void deg_init_kernel(float* deg) {
    int i = blockIdx.x * 256 + threadIdx.x;
    if (i < NN) deg[i] = 1.0f;
}

__global__ void edge_accum_kernel(const int* ei, const float* ea, float* deg, int* cnt) {
    int e = blockIdx.x * 256 + threadIdx.x;
    if (e >= EE) return;
    int d = ei[EE + e];
    float w = ea[e * 2 + 1];
    atomicAdd(&deg[d], w);
    atomicAdd(&cnt[d], 1);
}

__global__ void dinv_kernel(const float* deg, float* dinv) {
    int i = blockIdx.x * 256 + threadIdx.x;
    if (i < NN) dinv[i] = rsqrtf(deg[i]);
}

__global__ void scan_kernel(const int* cnt, int* rowptr, int* cursor) {
    __shared__ int wsum[16];
    int tid = threadIdx.x;
    int lane = tid & 63, w = tid >> 6;
    int run = 0;
    for (int base = 0; base < NN; base += 1024) {
        int idx = base + tid;
        int c = (idx < NN) ? cnt[idx] : 0;
        int v = c;
        #pragma unroll
        for (int off = 1; off < 64; off <<= 1) {
            int t = __shfl_up(v, off, 64);
            if (lane >= off) v += t;
        }
        if (lane == 63) wsum[w] = v;
        __syncthreads();
        if (tid < 16) {
            int x = wsum[tid];
            #pragma unroll
            for (int off = 1; off < 16; off <<= 1) {
                int t = __shfl_up(x, off, 64);
                if (tid >= off) x += t;
            }
            wsum[tid] = x;
        }
        __syncthreads();
        int waveoff = (w > 0) ? wsum[w - 1] : 0;
        int excl = run + waveoff + (v - c);
        if (idx < NN) { rowptr[idx] = excl; cursor[idx] = excl; }
        run += wsum[15];
        __syncthreads();
    }
    if (tid == 0) rowptr[NN] = run;
}

__global__ void fill_kernel(const int* ei, const float* ea, const float* dinv,
                            int* cursor, int* colIdx, float* valArr) {
    int e = blockIdx.x * 256 + threadIdx.x;
    if (e >= EE) return;
    int s = ei[e], d = ei[EE + e];
    float w = ea[e * 2 + 1];
    int pos = atomicAdd(&cursor[d], 1);
    colIdx[pos] = s;
    valArr[pos] = dinv[s] * w * dinv[d];
}

// x (N,F,T) fp32 -> xTs (T,N,F) bf16
__global__ void transpose_kernel(const float* x, unsigned short* xTs) {
    int i = blockIdx.x * 256 + threadIdx.x;
    if (i >= TT * NN * FF) return;
    int f = i & 31;
    int rest = i >> 5;
    int n = rest % NN;
    int t = rest / NN;
    xTs[i] = bf16rne(x[n * (FF * TT) + f * TT + t]);
}

// all 9 weight conversions in one launch; *T variants transpose (K,64)->[64][K]
__global__ void wconv_all(const float* Wg0, const float* Wu0, const float* Wr0, const float* Wc0,
                          const float* Wg1, const float* Wu1, const float* Wr1, const float* Wc1,
                          const float* ipw,
                          short* Wg0T, short* Wu0T, short* Wr0T, short* Wc0T,
                          short* Wg1T, short* Wu1T, short* Wr1T, short* Wc1T, short* ipwB) {
    int i = blockIdx.x * 256 + threadIdx.x;
    if (i < 2048) { int n = i / 32, k = i % 32; Wg0T[i] = (short)bf16rne(Wg0[k * 64 + n]); return; }
    i -= 2048;
    if (i < 10240) { int n = i / 160, k = i % 160; Wu0T[i] = (short)bf16rne(Wu0[k * 64 + n]); return; }
    i -= 10240;
    if (i < 10240) { int n = i / 160, k = i % 160; Wr0T[i] = (short)bf16rne(Wr0[k * 64 + n]); return; }
    i -= 10240;
    if (i < 10240) { int n = i / 160, k = i % 160; Wc0T[i] = (short)bf16rne(Wc0[k * 64 + n]); return; }
    i -= 10240;
    if (i < 4096) { int n = i / 64, k = i % 64; Wg1T[i] = (short)bf16rne(Wg1[k * 64 + n]); return; }
    i -= 4096;
    if (i < 12288) { int n = i / 192, k = i % 192; Wu1T[i] = (short)bf16rne(Wu1[k * 64 + n]); return; }
    i -= 12288;
    if (i < 12288) { int n = i / 192, k = i % 192; Wr1T[i] = (short)bf16rne(Wr1[k * 64 + n]); return; }
    i -= 12288;
    if (i < 12288) { int n = i / 192, k = i % 192; Wc1T[i] = (short)bf16rne(Wc1[k * 64 + n]); return; }
    i -= 12288;
    if (i < 12288) { ipwB[i] = (short)bf16rne(ipw[i]); }
}

// fold output projections: OW2[k][d] = sum_j opw[j][k]*ow[j][d]; ob2[d] = sum_j opb[j]*ow[j][d] + ob[d]
__global__ void fold_out(const float* opw, const float* opb, const float* ow, const float* ob,
                         float* OW2, float* ob2) {
    int i = blockIdx.x * 256 + threadIdx.x;
    if (i < 64 * OUTD) {
        int k = i / OUTD, d = i - k * OUTD;
        float acc = 0.f;
        for (int j = 0; j < 64; ++j) acc += opw[j * 64 + k] * ow[j * OUTD + d];
        OW2[i] = acc;
    } else if (i < 64 * OUTD + OUTD) {
        int d = i - 64 * OUTD;
        float acc = ob[d];
        for (int j = 0; j < 64; ++j) acc += opb[j] * ow[j * OUTD + d];
        ob2[d] = acc;
    }
}

// bf16 aggregation over x planes: 16 lanes/node, 2 features per lane
__global__ void gather_raw32(const unsigned short* __restrict__ xTs, const float* __restrict__ dinv,
                             const int* __restrict__ rowptr, const int* __restrict__ colIdx,
                             const float* __restrict__ valArr, unsigned short* __restrict__ aggxs) {
    const unsigned* src = (const unsigned*)(xTs + (size_t)blockIdx.y * NN * 32);
    unsigned* dst = (unsigned*)(aggxs + (size_t)blockIdx.y * NN * 32);
    int node = blockIdx.x * 16 + (threadIdx.x >> 4);
    int l2 = threadIdx.x & 15;
    float di = dinv[node];
    float dd = di * di;
    unsigned v = src[node * 16 + l2];
    float a0 = dd * lof(v), a1 = dd * hif(v);
    int s = rowptr[node], e = rowptr[node + 1];
    int j = s;
    for (; j + 3 < e; j += 4) {
        int c0 = colIdx[j], c1 = colIdx[j + 1], c2 = colIdx[j + 2], c3 = colIdx[j + 3];
        float w0 = valArr[j], w1 = valArr[j + 1], w2 = valArr[j + 2], w3 = valArr[j + 3];
        unsigned v0 = src[c0 * 16 + l2], v1 = src[c1 * 16 + l2];
        unsigned v2 = src[c2 * 16 + l2], v3 = src[c3 * 16 + l2];
        a0 += w0 * lof(v0) + w1 * lof(v1) + w2 * lof(v2) + w3 * lof(v3);
        a1 += w0 * hif(v0) + w1 * hif(v1) + w2 * hif(v2) + w3 * hif(v3);
    }
    for (; j < e; ++j) {
        unsigned vv = src[colIdx[j] * 16 + l2];
        float w = valArr[j];
        a0 += w * lof(vv); a1 += w * hif(vv);
    }
    dst[node * 16 + l2] = packbf(a0, a1);
}

// gather y0 (bf16) + sigmoid -> g1 (bf16): 32 lanes/node, fully parallel (one round/thread)
__global__ void gather_g1(const unsigned short* __restrict__ y0s, const float* __restrict__ dinv,
                          const int* __restrict__ rowptr, const int* __restrict__ colIdx,
                          const float* __restrict__ valArr, const float* __restrict__ bg1,
                          unsigned short* __restrict__ g1s) {
    const unsigned* yp = (const unsigned*)y0s;
    int node = blockIdx.x * 8 + (threadIdx.x >> 5);
    int l2 = threadIdx.x & 31;
    float di = dinv[node];
    float dd = di * di;
    unsigned v = yp[node * 32 + l2];
    float a0 = dd * lof(v), a1 = dd * hif(v);
    int s = rowptr[node], e = rowptr[node + 1];
    int j = s;
    for (; j + 3 < e; j += 4) {
        int c0 = colIdx[j], c1 = colIdx[j + 1], c2 = colIdx[j + 2], c3 = colIdx[j + 3];
        float w0 = valArr[j], w1 = valArr[j + 1], w2 = valArr[j + 2], w3 = valArr[j + 3];
        unsigned v0 = yp[c0 * 32 + l2], v1 = yp[c1 * 32 + l2];
        unsigned v2 = yp[c2 * 32 + l2], v3 = yp[c3 * 32 + l2];
        a0 += w0 * lof(v0) + w1 * lof(v1) + w2 * lof(v2) + w3 * lof(v3);
        a1 += w0 * hif(v0) + w1 * hif(v1) + w2 * hif(v2) + w3 * hif(v3);
    }
    for (; j < e; ++j) {
        unsigned vv = yp[colIdx[j] * 32 + l2];
        float w = valArr[j];
        a0 += w * lof(vv); a1 += w * hif(vv);
    }
    float g0v = sigmoidf_(a0 + bg1[2 * l2]);
    float g1v = sigmoidf_(a1 + bg1[2 * l2 + 1]);
    ((unsigned*)g1s)[node * 32 + l2] = packbf(g0v, g1v);
}

// ---------------- MFMA kernels ----------------
// A[m=lane&15][k=quad*8+j]; B^T[n=lane&15][k=quad*8+j]; C/D: col=lane&15, row=quad*4+reg.

// g0all = sigmoid(aggx @ Wg0 + bg0) -> bf16, rows = T*N, K=32
__launch_bounds__(256, 4)
__global__ void mfma_g0(const unsigned short* __restrict__ aggxs, const short* __restrict__ Wg0T,
                        const float* __restrict__ bg0, unsigned short* __restrict__ g0s) {
    int tid = threadIdx.x;
    int wv = tid >> 6, lane = tid & 63;
    int quad = lane >> 4, ln = lane & 15;
    int m0 = blockIdx.x * 64 + wv * 16;
    short8 af = *reinterpret_cast<const short8*>(aggxs + (size_t)(m0 + ln) * 32 + quad * 8);
    floatx4 z = {0.f, 0.f, 0.f, 0.f};
    floatx4 acc[4] = {z, z, z, z};
    #pragma unroll
    for (int ct = 0; ct < 4; ++ct) {
        short8 bf = *reinterpret_cast<const short8*>(Wg0T + (size_t)(ct * 16 + ln) * 32 + quad * 8);
        acc[ct] = MFMA(af, bf, acc[ct]);
    }
    #pragma unroll
    for (int ct = 0; ct < 4; ++ct) {
        int col = ct * 16 + ln;
        float bb = bg0[col];
        #pragma unroll
        for (int r = 0; r < 4; ++r) {
            int row = m0 + quad * 4 + r;
            g0s[(size_t)row * 64 + col] = bf16rne(sigmoidf_(acc[ct][r] + bb));
        }
    }
}

// ---- cell bodies (per-wave 16-row tile, wave-private LDS slice T) ----

__device__ __forceinline__ void cell0_body(
    int m0, short* T,
    const unsigned short* __restrict__ xt, const unsigned short* __restrict__ g0,
    const float* __restrict__ h0f, const unsigned short* __restrict__ h0s,
    const short* __restrict__ Wu0T, const short* __restrict__ Wr0T,
    const short* __restrict__ Wc0T, const short* __restrict__ Wg1T,
    const float* __restrict__ bu0, const float* __restrict__ br0,
    const float* __restrict__ bc0,
    float* __restrict__ h0nf, unsigned short* __restrict__ h0ns,
    unsigned short* __restrict__ y0s) {
    int lane = threadIdx.x & 63;
    int quad = lane >> 4, ln = lane & 15;
    int arow = m0 + ln; if (arow > NN - 1) arow = NN - 1;

    short8 af[5];
    af[0] = *reinterpret_cast<const short8*>(xt + (size_t)arow * 32 + quad * 8);
    af[1] = *reinterpret_cast<const short8*>(g0 + (size_t)arow * 64 + quad * 8);
    af[2] = *reinterpret_cast<const short8*>(g0 + (size_t)arow * 64 + 32 + quad * 8);
    af[3] = *reinterpret_cast<const short8*>(h0s + (size_t)arow * 64 + quad * 8);
    af[4] = *reinterpret_cast<const short8*>(h0s + (size_t)arow * 64 + 32 + quad * 8);

    floatx4 z = {0.f, 0.f, 0.f, 0.f};
    floatx4 aU[4] = {z, z, z, z};
    floatx4 aR[4] = {z, z, z, z};
    #pragma unroll
    for (int ct = 0; ct < 4; ++ct) {
        const short* bu = Wu0T + (size_t)(ct * 16 + ln) * 160;
        const short* br = Wr0T + (size_t)(ct * 16 + ln) * 160;
        #pragma unroll
        for (int kc = 0; kc < 5; ++kc) {
            int ko = kc * 32 + quad * 8;
            aU[ct] = MFMA(af[kc], *reinterpret_cast<const short8*>(bu + ko), aU[ct]);
            aR[ct] = MFMA(af[kc], *reinterpret_cast<const short8*>(br + ko), aR[ct]);
        }
    }
    float uu[4][4];
    #pragma unroll
    for (int ct = 0; ct < 4; ++ct) {
        int col = ct * 16 + ln;
        float bU = bu0[col], bR = br0[col];
        #pragma unroll
        for (int r = 0; r < 4; ++r) {
            int grow = m0 + quad * 4 + r;
            bool ok = grow < NN;
            uu[ct][r] = sigmoidf_(aU[ct][r] + bU);
            float hv = ok ? h0f[(size_t)grow * 64 + col] : 0.f;
            float rh = sigmoidf_(aR[ct][r] + bR) * hv;
            T[(quad * 4 + r) * 72 + col] = (short)bf16rne(rh);
        }
    }
    __threadfence_block();

    short8 ar0 = *reinterpret_cast<const short8*>(T + ln * 72 + quad * 8);
    short8 ar1 = *reinterpret_cast<const short8*>(T + ln * 72 + 32 + quad * 8);
    floatx4 aC[4] = {z, z, z, z};
    #pragma unroll
    for (int ct = 0; ct < 4; ++ct) {
        const short* bc = Wc0T + (size_t)(ct * 16 + ln) * 160;
        #pragma unroll
        for (int kc = 0; kc < 3; ++kc)
            aC[ct] = MFMA(af[kc], *reinterpret_cast<const short8*>(bc + kc * 32 + quad * 8), aC[ct]);
        aC[ct] = MFMA(ar0, *reinterpret_cast<const short8*>(bc + 96 + quad * 8), aC[ct]);
        aC[ct] = MFMA(ar1, *reinterpret_cast<const short8*>(bc + 128 + quad * 8), aC[ct]);
    }
    __threadfence_block();
    #pragma unroll
    for (int ct = 0; ct < 4; ++ct) {
        int col = ct * 16 + ln;
        float bC = bc0[col];
        #pragma unroll
        for (int r = 0; r < 4; ++r) {
            int grow = m0 + quad * 4 + r;
            bool ok = grow < NN;
            float hv = ok ? h0f[(size_t)grow * 64 + col] : 0.f;
            float cv = tanhf(aC[ct][r] + bC);
            float hn = uu[ct][r] * hv + (1.f - uu[ct][r]) * cv;
            unsigned short hb = bf16rne(hn);
            if (ok) {
                h0nf[(size_t)grow * 64 + col] = hn;
                h0ns[(size_t)grow * 64 + col] = hb;
            }
            T[(quad * 4 + r) * 72 + col] = (short)hb;
        }
    }
    __threadfence_block();

    short8 ah0 = *reinterpret_cast<const short8*>(T + ln * 72 + quad * 8);
    short8 ah1 = *reinterpret_cast<const short8*>(T + ln * 72 + 32 + quad * 8);
    floatx4 aY[4] = {z, z, z, z};
    #pragma unroll
    for (int ct = 0; ct < 4; ++ct) {
        const short* bg = Wg1T + (size_t)(ct * 16 + ln) * 64;
        aY[ct] = MFMA(ah0, *reinterpret_cast<const short8*>(bg + quad * 8), aY[ct]);
        aY[ct] = MFMA(ah1, *reinterpret_cast<const short8*>(bg + 32 + quad * 8), aY[ct]);
    }
    #pragma unroll
    for (int ct = 0; ct < 4; ++ct) {
        int col = ct * 16 + ln;
        #pragma unroll
        for (int r = 0; r < 4; ++r) {
            int grow = m0 + quad * 4 + r;
            if (grow < NN) y0s[(size_t)grow * 64 + col] = bf16rne(aY[ct][r]);
        }
    }
}

__device__ __forceinline__ void cell1_body(
    int m0, short* T,
    const unsigned short* __restrict__ h0s, const unsigned short* __restrict__ g1s,
    const float* __restrict__ h1f, const unsigned short* __restrict__ h1s,
    const short* __restrict__ Wu1T, const short* __restrict__ Wr1T,
    const short* __restrict__ Wc1T,
    const float* __restrict__ bu1, const float* __restrict__ br1,
    const float* __restrict__ bc1,
    float* __restrict__ h1nf, unsigned short* __restrict__ h1ns) {
    int lane = threadIdx.x & 63;
    int quad = lane >> 4, ln = lane & 15;
    int arow = m0 + ln; if (arow > NN - 1) arow = NN - 1;

    short8 af[6];
    af[0] = *reinterpret_cast<const short8*>(h0s + (size_t)arow * 64 + quad * 8);
    af[1] = *reinterpret_cast<const short8*>(h0s + (size_t)arow * 64 + 32 + quad * 8);
    af[2] = *reinterpret_cast<const short8*>(g1s + (size_t)arow * 64 + quad * 8);
    af[3] = *reinterpret_cast<const short8*>(g1s + (size_t)arow * 64 + 32 + quad * 8);
    af[4] = *reinterpret_cast<const short8*>(h1s + (size_t)arow * 64 + quad * 8);
    af[5] = *reinterpret_cast<const short8*>(h1s + (size_t)arow * 64 + 32 + quad * 8);

    floatx4 z = {0.f, 0.f, 0.f, 0.f};
    floatx4 aU[4] = {z, z, z, z};
    floatx4 aR[4] = {z, z, z, z};
    #pragma unroll
    for (int ct = 0; ct < 4; ++ct) {
        const short* bu = Wu1T + (size_t)(ct * 16 + ln) * 192;
        const short* br = Wr1T + (size_t)(ct * 16 + ln) * 192;
        #pragma unroll
        for (int kc = 0; kc < 6; ++kc) {
            int ko = kc * 32 + quad * 8;
            aU[ct] = MFMA(af[kc], *reinterpret_cast<const short8*>(bu + ko), aU[ct]);
            aR[ct] = MFMA(af[kc], *reinterpret_cast<const short8*>(br + ko), aR[ct]);
        }
    }
    float uu[4][4];
    #pragma unroll
    for (int ct = 0; ct < 4; ++ct) {
        int col = ct * 16 + ln;
        float bU = bu1[col], bR = br1[col];
        #pragma unroll
        for (int r = 0; r < 4; ++r) {
            int grow = m0 + quad * 4 + r;
            bool ok = grow < NN;
            uu[ct][r] = sigmoidf_(aU[ct][r] + bU);
            float hv = ok ? h1f[(size_t)grow * 64 + col] : 0.f;
            float rh = sigmoidf_(aR[ct][r] + bR) * hv;
            T[(quad * 4 + r) * 72 + col] = (short)bf16rne(rh);
        }
    }
    __threadfence_block();

    short8 ar0 = *reinterpret_cast<const short8*>(T + ln * 72 + quad * 8);
    short8 ar1 = *reinterpret_cast<const short8*>(T + ln * 72 + 32 + quad * 8);
    floatx4 aC[4] = {z, z, z, z};
    #pragma unroll
    for (int ct = 0; ct < 4; ++ct) {
        const short* bc = Wc1T + (size_t)(ct * 16 + ln) * 192;
        #pragma unroll
        for (int kc = 0; kc < 4; ++kc)
            aC[ct] = MFMA(af[kc], *reinterpret_cast<const short8*>(bc + kc * 32 + quad * 8), aC[ct]);
        aC[ct] = MFMA(ar0, *reinterpret_cast<const short8*>(bc + 128 + quad * 8), aC[ct]);
        aC[ct] = MFMA(ar1, *reinterpret_cast<const short8*>(bc + 160 + quad * 8), aC[ct]);
    }
    #pragma unroll
    for (int ct = 0; ct < 4; ++ct) {
        int col = ct * 16 + ln;
        float bC = bc1[col];
        #pragma unroll
        for (int r = 0; r < 4; ++r) {
            int grow = m0 + quad * 4 + r;
            if (grow >= NN) continue;
            float hv = h1f[(size_t)grow * 64 + col];
            float cv = tanhf(aC[ct][r] + bC);
            float hn = uu[ct][r] * hv + (1.f - uu[ct][r]) * cv;
            h1nf[(size_t)grow * 64 + col] = hn;
            h1ns[(size_t)grow * 64 + col] = bf16rne(hn);
        }
    }
}

// standalone cell0 (t=0 bootstrap)
__launch_bounds__(256, 4)
__global__ void mfma_cell0(const unsigned short* xt, const unsigned short* g0,
                           const float* h0f, const unsigned short* h0s,
                           const short* Wu0T, const short* Wr0T, const short* Wc0T, const short* Wg1T,
                           const float* bu0, const float* br0, const float* bc0,
                           float* h0nf, unsigned short* h0ns, unsigned short* y0s) {
    __shared__ short lds[4 * 16 * 72];
    int wv = threadIdx.x >> 6;
    cell0_body(blockIdx.x * 64 + wv * 16, lds + wv * (16 * 72),
               xt, g0, h0f, h0s, Wu0T, Wr0T, Wc0T, Wg1T, bu0, br0, bc0, h0nf, h0ns, y0s);
}

// merged step: blocks [0,CB) = cell1 for t; blocks [CB,2CB) = cell0 for t+1 (independent)
__launch_bounds__(256, 4)
__global__ void mfma_step(
    const unsigned short* h0s_cur, const unsigned short* g1s,
    const float* h1f_in, const unsigned short* h1s_in,
    const short* Wu1T, const short* Wr1T, const short* Wc1T,
    const float* bu1, const float* br1, const float* bc1,
    float* h1f_out, unsigned short* h1s_out,
    const unsigned short* xt_next, const unsigned short* g0_next, const float* h0f_cur,
    const short* Wu0T, const short* Wr0T, const short* Wc0T, const short* Wg1T,
    const float* bu0, const float* br0, const float* bc0,
    float* h0f_next, unsigned short* h0s_next, unsigned short* y0s) {
    __shared__ short lds[4 * 16 * 72];
    int wv = threadIdx.x >> 6;
    short* T = lds + wv * (16 * 72);
    if (blockIdx.x < CB) {
        cell1_body(blockIdx.x * 64 + wv * 16, T, h0s_cur, g1s, h1f_in, h1s_in,
                   Wu1T, Wr1T, Wc1T, bu1, br1, bc1, h1f_out, h1s_out);
    } else {
        cell0_body((blockIdx.x - CB) * 64 + wv * 16, T, xt_next, g0_next, h0f_cur, h0s_cur,
                   Wu0T, Wr0T, Wc0T, Wg1T, bu0, br0, bc0, h0f_next, h0s_next, y0s);
    }
}

// ---------------- fused qkv + attention: one wave per node ----------------
__launch_bounds__(256, 5)
__global__ void attn_fused(const unsigned short* __restrict__ hseqs,
                           const short* __restrict__ ipwB, const float* __restrict__ ipb,
                           const float* __restrict__ OW2, const float* __restrict__ ob2,
                           float* __restrict__ out) {
    __shared__ unsigned short qtile[4][16 * 200];
    __shared__ float fbuf[4][64];
    __shared__ float wbuf[4][32];
    int wv = threadIdx.x >> 6, lane = threadIdx.x & 63;
    int node = blockIdx.x * 4 + wv;
    int quad = lane >> 4, ln = lane & 15;
    unsigned short* q = qtile[wv];
    float* sob = fbuf[wv];       // obar[64]
    float* W = wbuf[wv];         // [2][16] head-major mean-prob weights

    // ---- qkv tile via MFMA from hseqs ----
    short8 zero8 = {0, 0, 0, 0, 0, 0, 0, 0};
    short8 af0 = zero8, af1 = zero8;
    if (ln < TT) {
        const unsigned short* hp = hseqs + ((size_t)ln * NN + node) * 64;
        af0 = *reinterpret_cast<const short8*>(hp + quad * 8);
        af1 = *reinterpret_cast<const short8*>(hp + 32 + quad * 8);
    }
    floatx4 z = {0.f, 0.f, 0.f, 0.f};
    #pragma unroll
    for (int ct = 0; ct < 12; ++ct) {
        const short* br = ipwB + (size_t)(ct * 16 + ln) * 64;
        floatx4 acc = MFMA(af0, *reinterpret_cast<const short8*>(br + quad * 8), z);
        acc = MFMA(af1, *reinterpret_cast<const short8*>(br + 32 + quad * 8), acc);
        int col = ct * 16 + ln;
        float bb = ipb[col];
        #pragma unroll
        for (int r = 0; r < 4; ++r)
            q[(quad * 4 + r) * 200 + col] = bf16rne(acc[r] + bb);
    }
    __threadfence_block();

    // ---- scores per head via one MFMA ----
    floatx4 sc[2];
    #pragma unroll
    for (int h = 0; h < 2; ++h) {
        short8 aQ = *reinterpret_cast<const short8*>(q + ln * 200 + h * 32 + quad * 8);
        short8 bK = *reinterpret_cast<const short8*>(q + ln * 200 + 64 + h * 32 + quad * 8);
        sc[h] = MFMA(aQ, bK, z);   // rows=tq(quad*4+r), cols=ts(ln)
    }
    const float scl = 0.17677669529663687f;
    bool colok = ln < 12;
    #pragma unroll
    for (int h = 0; h < 2; ++h) {
        float p[4];
        #pragma unroll
        for (int r = 0; r < 4; ++r) {
            float v = colok ? sc[h][r] * scl : -1e30f;
            float m = v;
            m = fmaxf(m, __shfl_xor(m, 1, 64));
            m = fmaxf(m, __shfl_xor(m, 2, 64));
            m = fmaxf(m, __shfl_xor(m, 4, 64));
            m = fmaxf(m, __shfl_xor(m, 8, 64));
            float e = colok ? expf(v - m) : 0.f;
            float s = e;
            s += __shfl_xor(s, 1, 64);
            s += __shfl_xor(s, 2, 64);
            s += __shfl_xor(s, 4, 64);
            s += __shfl_xor(s, 8, 64);
            p[r] = e / s;
        }
        float ts = (quad < 3) ? (p[0] + p[1] + p[2] + p[3]) : 0.f;
        ts += __shfl_xor(ts, 16, 64);
        ts += __shfl_xor(ts, 32, 64);
        if (quad == 0) W[h * 16 + ln] = ts * (1.f / 12.f);
    }
    __threadfence_block();

    // ---- obar[d] = sum_ts w[hd][ts] * V[ts][d] ----
    {
        int d = lane, hd = d >> 5, dd = d & 31;
        float acc = 0.f;
        #pragma unroll
        for (int ts = 0; ts < 12; ++ts)
            acc += W[hd * 16 + ts] * lof((unsigned)q[ts * 200 + 128 + hd * 32 + dd]);
        sob[d] = acc;
    }
    __threadfence_block();

    // ---- out = obar @ OW2 + ob2 (folded projections) ----
    if (lane < OUTD) {
        float acc = ob2[lane];
        #pragma unroll
        for (int k = 0; k < 64; ++k) acc += sob[k] * OW2[k * OUTD + lane];
        out[(size_t)node * OUTD + lane] = acc;
    }
}

// ---------------- launcher ----------------

extern "C" void kernel_launch(void* const* d_in, const int* in_sizes, int n_in,
                              void* d_out, int out_size, void* d_ws, size_t ws_size,
                              hipStream_t stream) {
    const float* x   = (const float*)d_in[0];
    const int*   ei  = (const int*)d_in[1];
    const float* ea  = (const float*)d_in[2];
    const float* Wg0 = (const float*)d_in[3];
    const float* bg0 = (const float*)d_in[4];
    const float* Wu0 = (const float*)d_in[5];
    const float* bu0 = (const float*)d_in[6];
    const float* Wr0 = (const float*)d_in[7];
    const float* br0 = (const float*)d_in[8];
    const float* Wc0 = (const float*)d_in[9];
    const float* bc0 = (const float*)d_in[10];
    const float* Wg1 = (const float*)d_in[11];
    const float* bg1 = (const float*)d_in[12];
    const float* Wu1 = (const float*)d_in[13];
    const float* bu1 = (const float*)d_in[14];
    const float* Wr1 = (const float*)d_in[15];
    const float* br1 = (const float*)d_in[16];
    const float* Wc1 = (const float*)d_in[17];
    const float* bc1 = (const float*)d_in[18];
    const float* ipw = (const float*)d_in[19];
    const float* ipb = (const float*)d_in[20];
    const float* opw = (const float*)d_in[21];
    const float* opb = (const float*)d_in[22];
    const float* ow  = (const float*)d_in[23];
    const float* ob  = (const float*)d_in[24];
    float* out = (float*)d_out;

    char* p = (char*)d_ws;
    auto alloc = [&](size_t bytes) { char* r = p; p += (bytes + 255) & ~(size_t)255; return (void*)r; };
    unsigned short* hseqs = (unsigned short*)alloc((size_t)TT * NN * HH * 2);
    unsigned short* h1s0  = (unsigned short*)alloc((size_t)NN * HH * 2);
    short* Wg0T = (short*)alloc((size_t)64 * 32 * 2);
    short* Wu0T = (short*)alloc((size_t)64 * 160 * 2);
    short* Wr0T = (short*)alloc((size_t)64 * 160 * 2);
    short* Wc0T = (short*)alloc((size_t)64 * 160 * 2);
    short* Wg1T = (short*)alloc((size_t)64 * 64 * 2);
    short* Wu1T = (short*)alloc((size_t)64 * 192 * 2);
    short* Wr1T = (short*)alloc((size_t)64 * 192 * 2);
    short* Wc1T = (short*)alloc((size_t)64 * 192 * 2);
    short* ipwB = (short*)alloc((size_t)192 * 64 * 2);
    float* OW2  = (float*)alloc((size_t)64 * OUTD * 4);
    float* ob2  = (float*)alloc((size_t)OUTD * 4);
    float* dinv   = (float*)alloc((size_t)NN * 4);
    int*   rowptr = (int*)  alloc((size_t)(NN + 1) * 4);
    int*   colIdx = (int*)  alloc((size_t)EE * 4);
    float* valArr = (float*)alloc((size_t)EE * 4);
    unsigned short* xTs   = (unsigned short*)alloc((size_t)TT * NN * FF * 2);
    unsigned short* aggxs = (unsigned short*)alloc((size_t)TT * NN * FF * 2);
    unsigned short* g0s   = (unsigned short*)alloc((size_t)TT * NN * HH * 2);
    float* deg    = (float*)alloc((size_t)NN * 4);
    int*   cnt    = (int*)  alloc((size_t)NN * 4);
    int*   cursor = (int*)  alloc((size_t)NN * 4);
    unsigned short* y0s = (unsigned short*)alloc((size_t)NN * HH * 2);
    unsigned short* g1s = (unsigned short*)alloc((size_t)NN * HH * 2);
    float* h0f0 = (float*)alloc((size_t)NN * HH * 4);
    float* h0f1 = (float*)alloc((size_t)NN * HH * 4);
    float* h1f0 = (float*)alloc((size_t)NN * HH * 4);
    float* h1f1 = (float*)alloc((size_t)NN * HH * 4);
    unsigned short* h0s0 = (unsigned short*)alloc((size_t)NN * HH * 2);
    unsigned short* h0s1 = (unsigned short*)alloc((size_t)NN * HH * 2);
    (void)ws_size;

    hipMemsetAsync(cnt, 0, (size_t)NN * 4, stream);
    hipMemsetAsync(h0f1, 0, (size_t)NN * HH * 4, stream);
    hipMemsetAsync(h1f1, 0, (size_t)NN * HH * 4, stream);
    hipMemsetAsync(h0s1, 0, (size_t)NN * HH * 2, stream);
    hipMemsetAsync(h1s0, 0, (size_t)NN * HH * 2, stream);
    deg_init_kernel<<<(NN + 255) / 256, 256, 0, stream>>>(deg);
    edge_accum_kernel<<<(EE + 255) / 256, 256, 0, stream>>>(ei, ea, deg, cnt);
    dinv_kernel<<<(NN + 255) / 256, 256, 0, stream>>>(deg, dinv);
    scan_kernel<<<1, 1024, 0, stream>>>(cnt, rowptr, cursor);
    fill_kernel<<<(EE + 255) / 256, 256, 0, stream>>>(ei, ea, dinv, cursor, colIdx, valArr);
    transpose_kernel<<<(TT * NN * FF + 255) / 256, 256, 0, stream>>>(x, xTs);
    wconv_all<<<(86016 + 255) / 256, 256, 0, stream>>>(
        Wg0, Wu0, Wr0, Wc0, Wg1, Wu1, Wr1, Wc1, ipw,
        Wg0T, Wu0T, Wr0T, Wc0T, Wg1T, Wu1T, Wr1T, Wc1T, ipwB);
    fold_out<<<4, 256, 0, stream>>>(opw, opb, ow, ob, OW2, ob2);

    gather_raw32<<<dim3(NN / 16, TT), 256, 0, stream>>>(xTs, dinv, rowptr, colIdx, valArr, aggxs);
    mfma_g0<<<(TT * NN) / 64, 256, 0, stream>>>(aggxs, Wg0T, bg0, g0s);

    float* h0f[2] = {h0f0, h0f1};
    unsigned short* h0s[2] = {h0s0, h0s1};
    float* h1f[2] = {h1f0, h1f1};

    // C0[0]: reads zeroed buf[1], writes buf[0]
    mfma_cell0<<<CB, 256, 0, stream>>>(
        xTs, g0s, h0f[1], h0s[1], Wu0T, Wr0T, Wc0T, Wg1T, bu0, br0, bc0,
        h0f[0], h0s[0], y0s);

    for (int t = 0; t < TT; ++t) {
        gather_g1<<<NN / 8, 256, 0, stream>>>(y0s, dinv, rowptr, colIdx, valArr, bg1, g1s);
        int tn = (t < TT - 1) ? (t + 1) : t;   // dummy ptrs for t=11 (cell0 part not launched)
        int grid = (t < TT - 1) ? 2 * CB : CB;
        mfma_step<<<grid, 256, 0, stream>>>(
            h0s[t & 1], g1s, h1f[(t + 1) & 1],
            (t == 0) ? h1s0 : (hseqs + (size_t)(t - 1) * NN * HH),
            Wu1T, Wr1T, Wc1T, bu1, br1, bc1,
            h1f[t & 1], hseqs + (size_t)t * NN * HH,
            xTs + (size_t)tn * NN * FF, g0s + (size_t)tn * NN * HH, h0f[t & 1],
            Wu0T, Wr0T, Wc0T, Wg1T, bu0, br0, bc0,
            h0f[(t + 1) & 1], h0s[(t + 1) & 1], y0s);
    }

    attn_fused<<<NN / 4, 256, 0, stream>>>(hseqs, ipwB, ipb, OW2, ob2, out);
}